// Round 17
// baseline (1641.290 us; speedup 1.0000x reference)
//
#include <hip/hip_runtime.h>

#define N_NODES 131072
#define DIM     128
#define NGRAPH  1024
#define NEDGE   4194304

#define NW      512                   // dest windows (256 rows each)
#define WBINS   256                   // rows (bins) per window
#define NCW     8                     // col windows (16384 cols each)
#define HBINS   (WBINS * NCW)         // 2048 sort keys in winbuild
#define NSL     512                   // edge slices per hop
#define SLICE_E (NEDGE / NSL)         // 8192 edges per slice
#define CAP     12288                 // LDS col-image capacity (ints); mean 8192
#define SP_BATCH 16                   // rows per wave in spmm

typedef float floatx4 __attribute__((ext_vector_type(4)));
typedef float f32x4  __attribute__((ext_vector_type(4)));
typedef __bf16 bf16x8 __attribute__((ext_vector_type(8)));
typedef __bf16 bf16x4 __attribute__((ext_vector_type(4)));

// swizzled LDS byte offset for a [rows][128] bf16 tile (row stride 256 B)
__device__ __forceinline__ int lds_off(int row, int kb) {
    return row * 256 + (kb ^ ((row & 7) << 4));
}

// async global->LDS, 16 B per lane; LDS dest = wave-uniform base + lane*16
#define GLOAD16(gp, lp) __builtin_amdgcn_global_load_lds( \
    (const __attribute__((address_space(1))) void*)(gp),  \
    (__attribute__((address_space(3))) void*)(lp), 16, 0, 0)

__device__ __forceinline__ void stage_async(char* dstbase, const char* src,
                                            int w, int lane) {
#pragma unroll
    for (int it = 0; it < 8; ++it) {
        int chunk = it * 4 + w;
        int p = chunk * 1024 + lane * 16;
        int r = p >> 8;
        int o = p & 255;
        const char* g = src + r * 256 + (o ^ ((r & 7) << 4));
        GLOAD16(g, dstbase + chunk * 1024);
    }
}

// ---------------------------------------------------------------- zero
__global__ __launch_bounds__(256)
void zero_kernel(floatx4* __restrict__ p, long n4) {
    long i = (long)blockIdx.x * blockDim.x + threadIdx.x;
    long stride = (long)gridDim.x * blockDim.x;
    floatx4 z = {0.f, 0.f, 0.f, 0.f};
    for (; i < n4; i += stride) p[i] = z;
}

// ---------------------------------------------------------------- prep: fp32 -> bf16
__global__ __launch_bounds__(256)
void cvt_kernel(const float* __restrict__ src, __bf16* __restrict__ dst) {
    int i = blockIdx.x * 256 + threadIdx.x;
    const int stride = gridDim.x * 256;
    const int total = N_NODES * 32;
    for (; i < total; i += stride) {
        floatx4 v = ((const floatx4*)src)[i];
        bf16x4 h;
        h[0] = (__bf16)v[0]; h[1] = (__bf16)v[1];
        h[2] = (__bf16)v[2]; h[3] = (__bf16)v[3];
        ((bf16x4*)dst)[i] = h;
    }
}

__global__ __launch_bounds__(256)
void cvt_cat_kernel(const float* __restrict__ x, const float* __restrict__ rw,
                    __bf16* __restrict__ dst) {
    int i = blockIdx.x * 256 + threadIdx.x;
    const int stride = gridDim.x * 256;
    const int total = N_NODES * 32;
    for (; i < total; i += stride) {
        int rowg = i >> 5, g = i & 31;
        const float* s = (g < 16) ? x  + (size_t)rowg * 64 + g * 4
                                  : rw + (size_t)rowg * 64 + (g - 16) * 4;
        floatx4 v = *(const floatx4*)s;
        bf16x4 h;
        h[0] = (__bf16)v[0]; h[1] = (__bf16)v[1];
        h[2] = (__bf16)v[2]; h[3] = (__bf16)v[3];
        *(bf16x4*)(dst + (size_t)rowg * 128 + g * 4) = h;
    }
}

// ---------------------------------------------------------------- weight prep
__global__ __launch_bounds__(256)
void tr_kernel(const float* __restrict__ src, __bf16* __restrict__ dst, int nmat) {
    int idx = blockIdx.x * blockDim.x + threadIdx.x;
    int total = nmat * 16384;
    if (idx >= total) return;
    int m = idx >> 14;
    int col = (idx >> 7) & 127;
    int k = idx & 127;
    dst[idx] = (__bf16)src[m * 16384 + k * 128 + col];
}

// ---------------------------------------------------------------- CSR build v4
__global__ __launch_bounds__(256)
void wincount_kernel(const int* __restrict__ e1, const int* __restrict__ e2,
                     const int* __restrict__ e3, int* __restrict__ gcount) {
    const int gb = blockIdx.x;
    const int sl = gb % NSL;
    const int hop = gb / NSL;
    const int* rows = hop == 0 ? e1 : hop == 1 ? e2 : e3;

    __shared__ int cnt[NW];
    for (int i = threadIdx.x; i < NW; i += 256) cnt[i] = 0;
    __syncthreads();

    const int4* src = (const int4*)rows + (size_t)sl * (SLICE_E / 4);
    for (int j = threadIdx.x; j < SLICE_E / 4; j += 256) {
        int4 v = src[j];
        atomicAdd(&cnt[v.x >> 8], 1); atomicAdd(&cnt[v.y >> 8], 1);
        atomicAdd(&cnt[v.z >> 8], 1); atomicAdd(&cnt[v.w >> 8], 1);
    }
    __syncthreads();

    int* dst = gcount + ((size_t)hop * NSL + sl) * NW;
    for (int i = threadIdx.x; i < NW; i += 256) dst[i] = cnt[i];
}

__global__ __launch_bounds__(256)
void basescan_kernel(const int* __restrict__ gcount, int* __restrict__ baseo,
                     int* __restrict__ wbase) {
    const int hop = blockIdx.x;
    const int t = threadIdx.x;
    __shared__ int wt[NW];
    __shared__ int part[256];

    for (int k = 0; k < 2; ++k) {
        int w = t * 2 + k;
        int s = 0;
        for (int sl = 0; sl < NSL; ++sl)
            s += gcount[((size_t)hop * NSL + sl) * NW + w];
        wt[w] = s;
    }
    __syncthreads();
    part[t] = wt[2 * t] + wt[2 * t + 1];
    __syncthreads();
    for (int d = 1; d < 256; d <<= 1) {
        int v = (t >= d) ? part[t - d] : 0;
        __syncthreads();
        part[t] += v;
        __syncthreads();
    }
    int run = (t == 0) ? 0 : part[t - 1];
    for (int k = 0; k < 2; ++k) {
        int w = 2 * t + k;
        wbase[hop * (NW + 1) + w] = run;
        int r2 = run;
        for (int sl = 0; sl < NSL; ++sl) {
            baseo[((size_t)hop * NW + w) * NSL + sl] = r2;
            r2 += gcount[((size_t)hop * NSL + sl) * NW + w];
        }
        run += wt[w];
    }
    if (t == 255) wbase[hop * (NW + 1) + NW] = NEDGE;
}

// bucket: per (hop,slice) in-LDS counting sort by dest window, coalesced write-out
__global__ __launch_bounds__(256)
void bucket_kernel(const int* __restrict__ e1, const int* __restrict__ e2,
                   const int* __restrict__ e3, const int* __restrict__ baseo,
                   int* __restrict__ buf) {
    const int gb = blockIdx.x;
    const int sl = gb % NSL;
    const int hop = gb / NSL;
    const int* rows = hop == 0 ? e1 : hop == 1 ? e2 : e3;
    const int* cs = rows + NEDGE;
    const int t = threadIdx.x;

    __shared__ int hist[NW];
    __shared__ int segstart[NW + 1];
    __shared__ int part[256];
    __shared__ int image[SLICE_E];

    for (int i = t; i < NW; i += 256) hist[i] = 0;
    __syncthreads();

    const int4* r4 = (const int4*)rows + (size_t)sl * (SLICE_E / 4);
    const int4* c4 = (const int4*)cs + (size_t)sl * (SLICE_E / 4);
    for (int j = t; j < SLICE_E / 4; j += 256) {
        int4 v = r4[j];
        atomicAdd(&hist[v.x >> 8], 1); atomicAdd(&hist[v.y >> 8], 1);
        atomicAdd(&hist[v.z >> 8], 1); atomicAdd(&hist[v.w >> 8], 1);
    }
    __syncthreads();

    int a = hist[2 * t], b = hist[2 * t + 1];
    part[t] = a + b;
    __syncthreads();
    for (int d = 1; d < 256; d <<= 1) {
        int v = (t >= d) ? part[t - d] : 0;
        __syncthreads();
        part[t] += v;
        __syncthreads();
    }
    int base = (t == 0) ? 0 : part[t - 1];
    segstart[2 * t] = base;
    segstart[2 * t + 1] = base + a;
    if (t == 255) segstart[NW] = SLICE_E;
    __syncthreads();
    hist[2 * t] = base;
    hist[2 * t + 1] = base + a;
    __syncthreads();

    for (int j = t; j < SLICE_E / 4; j += 256) {
        int4 r = r4[j];
        int4 c = c4[j];
        int p;
        p = atomicAdd(&hist[r.x >> 8], 1); image[p] = ((r.x & 255) << 17) | c.x;
        p = atomicAdd(&hist[r.y >> 8], 1); image[p] = ((r.y & 255) << 17) | c.y;
        p = atomicAdd(&hist[r.z >> 8], 1); image[p] = ((r.z & 255) << 17) | c.z;
        p = atomicAdd(&hist[r.w >> 8], 1); image[p] = ((r.w & 255) << 17) | c.w;
    }
    __syncthreads();

    int* bufh = buf + (size_t)hop * NEDGE;
    const int* bo = baseo + (size_t)hop * NW * NSL + sl;
    for (int j = t; j < SLICE_E; j += 256) {
        int lo = 0, hi = NW;
        while (hi - lo > 1) {
            int mid = (lo + hi) >> 1;
            if (segstart[mid] <= j) lo = mid; else hi = mid;
        }
        int dst = bo[(size_t)lo * NSL] + (j - segstart[lo]);
        bufh[dst] = image[j];
    }
}

// winbuild v4: per (hop,window): sort entries by key (bin, colwindow),
// emit offs (per bin) + packed per-(bin,colwindow) counts + sorted col.
__global__ __launch_bounds__(256)
void winbuild_kernel(const int* __restrict__ buf, const int* __restrict__ wbase,
                     int* __restrict__ offs3, int* __restrict__ cols,
                     uint2* __restrict__ cnts3) {
    const int gb = blockIdx.x;
    const int w = gb % NW;
    const int hop = gb / NW;
    const int b0 = wbase[hop * (NW + 1) + w];
    const int b1 = wbase[hop * (NW + 1) + w + 1];
    const int tot = b1 - b0;
    const int* src = buf + (size_t)hop * NEDGE + b0;
    int* col = cols + (size_t)hop * NEDGE;
    int* offs = offs3 + (size_t)hop * (N_NODES + 1);
    uint2* cnts = cnts3 + (size_t)hop * N_NODES;
    const int t = threadIdx.x;

    __shared__ int hist[HBINS];       // 2048 keys
    __shared__ int part[256];
    __shared__ int image[CAP];

#pragma unroll
    for (int j = 0; j < NCW; ++j) hist[t * NCW + j] = 0;
    __syncthreads();

    // histogram by key = bin*8 + colwindow
    for (int i = t; i < tot; i += 256) {
        int e = src[i];
        int key = ((e >> 17) << 3) | ((e & 0x1FFFF) >> 14);
        atomicAdd(&hist[key], 1);
    }
    __syncthreads();

    // scan 2048 keys: thread t owns keys 8t..8t+7
    int loc[NCW];
    int s = 0;
#pragma unroll
    for (int j = 0; j < NCW; ++j) { loc[j] = hist[t * NCW + j]; s += loc[j]; }
    part[t] = s;
    __syncthreads();
    for (int d = 1; d < 256; d <<= 1) {
        int v = (t >= d) ? part[t - d] : 0;
        __syncthreads();
        part[t] += v;
        __syncthreads();
    }
    const int excl = part[t] - s;     // exclusive at key t*8

    offs[w * WBINS + t] = b0 + excl;
    if (w == NW - 1 && t == 0) offs[N_NODES] = NEDGE;

    // pack counts + write cursors back
    unsigned cx = 0, cy = 0;
    int run = excl;
#pragma unroll
    for (int j = 0; j < NCW; ++j) {
        if (j < 4) cx |= (unsigned)loc[j] << (8 * j);
        else       cy |= (unsigned)loc[j] << (8 * (j - 4));
        hist[t * NCW + j] = (tot <= CAP) ? run : b0 + run;
        run += loc[j];
    }
    cnts[w * WBINS + t] = make_uint2(cx, cy);
    __syncthreads();

    if (tot <= CAP) {
        for (int i = t; i < tot; i += 256) {
            int e = src[i];
            int key = ((e >> 17) << 3) | ((e & 0x1FFFF) >> 14);
            int p = atomicAdd(&hist[key], 1);
            image[p] = e & 0x1FFFF;
        }
        __syncthreads();
        for (int i = t; i < tot; i += 256) col[b0 + i] = image[i];
    } else {                          // overflow fallback (statistically never)
        for (int i = t; i < tot; i += 256) {
            int e = src[i];
            int key = ((e >> 17) << 3) | ((e & 0x1FFFF) >> 14);
            int p = atomicAdd(&hist[key], 1);
            col[p] = e & 0x1FFFF;
        }
    }
}

// ---------------------------------------------------------------- CSR spmm (bf16)
// pass-aligned over 8 col-windows: wave owns SP_BATCH rows; all waves process
// window p together -> gather working set 4MB = one XCD L2.
__global__ __launch_bounds__(256)
void csr_spmm_kernel(const int* __restrict__ offs,
                     const unsigned char* __restrict__ cntb,
                     const int* __restrict__ col,
                     const __bf16* __restrict__ xin, __bf16* __restrict__ outb) {
    const int lane = threadIdx.x & 63;
    const int wid = blockIdx.x * 4 + (threadIdx.x >> 6);
    const int row0 = wid * SP_BATCH;

    float a0[SP_BATCH], a1[SP_BATCH];
    int cur[SP_BATCH];
#pragma unroll
    for (int r = 0; r < SP_BATCH; ++r) {
        a0[r] = 0.f; a1[r] = 0.f;
        cur[r] = offs[row0 + r];
    }

    for (int p = 0; p < NCW; ++p) {
#pragma unroll 1
        for (int r = 0; r < SP_BATCH; ++r) {
            int len = cntb[(size_t)(row0 + r) * 8 + p];
            while (len > 0) {
                int n = min(len, 64);
                int cidx = (lane < n) ? col[cur[r] + lane] : 0;
                int i = 0;
                for (; i + 2 <= n; i += 2) {
                    int c0 = __shfl(cidx, i);
                    int c1 = __shfl(cidx, i + 1);
                    unsigned v0 = *(const unsigned*)(xin + (size_t)c0 * 128 + lane * 2);
                    unsigned v1 = *(const unsigned*)(xin + (size_t)c1 * 128 + lane * 2);
                    a0[r] += __uint_as_float(v0 << 16);
                    a1[r] += __uint_as_float(v0 & 0xffff0000u);
                    a0[r] += __uint_as_float(v1 << 16);
                    a1[r] += __uint_as_float(v1 & 0xffff0000u);
                }
                for (; i < n; ++i) {
                    int c = __shfl(cidx, i);
                    unsigned v = *(const unsigned*)(xin + (size_t)c * 128 + lane * 2);
                    a0[r] += __uint_as_float(v << 16);
                    a1[r] += __uint_as_float(v & 0xffff0000u);
                }
                cur[r] += n; len -= n;
            }
        }
    }

#pragma unroll
    for (int r = 0; r < SP_BATCH; ++r) {
        union { unsigned u; __bf16 h[2]; } pk;
        pk.h[0] = (__bf16)a0[r]; pk.h[1] = (__bf16)a1[r];
        *(unsigned*)(outb + (size_t)(row0 + r) * 128 + lane * 2) = pk.u;
    }
}

// ---------------------------------------------------------------- GEMM phases
__device__ __forceinline__ void mfma_relu_phase(char* az, const char* wb,
                                                const float* bias,
                                                int r0, int lrow, int grp) {
    bf16x8 am[2][4];
#pragma unroll
    for (int mt = 0; mt < 2; ++mt)
#pragma unroll
        for (int kk = 0; kk < 4; ++kk)
            am[mt][kk] = *(const bf16x8*)(az + lds_off(r0 + mt * 16 + lrow,
                                                       kk * 64 + grp * 16));
#pragma unroll
    for (int n = 0; n < 8; ++n) {
        f32x4 a0 = {0.f, 0.f, 0.f, 0.f};
        f32x4 a1 = {0.f, 0.f, 0.f, 0.f};
#pragma unroll
        for (int kk = 0; kk < 4; ++kk) {
            bf16x8 b = *(const bf16x8*)(wb + lds_off(n * 16 + lrow,
                                                     kk * 64 + grp * 16));
            a0 = __builtin_amdgcn_mfma_f32_16x16x32_bf16(am[0][kk], b, a0, 0, 0, 0);
            a1 = __builtin_amdgcn_mfma_f32_16x16x32_bf16(am[1][kk], b, a1, 0, 0, 0);
        }
        float bs = bias[n * 16 + lrow];
#pragma unroll
        for (int rg = 0; rg < 4; ++rg) {
            float v0 = fmaxf(a0[rg] + bs, 0.f);
            float v1 = fmaxf(a1[rg] + bs, 0.f);
            *(__bf16*)(az + lds_off(r0 + grp * 4 + rg, (n * 16 + lrow) * 2)) = (__bf16)v0;
            *(__bf16*)(az + lds_off(r0 + 16 + grp * 4 + rg, (n * 16 + lrow) * 2)) = (__bf16)v1;
        }
    }
}

__device__ __forceinline__ void mfma_phase(const char* az, const char* wb,
                                           int r0, int lrow, int grp,
                                           f32x4 (&acc)[2][8]) {
    bf16x8 am[2][4];
#pragma unroll
    for (int mt = 0; mt < 2; ++mt)
#pragma unroll
        for (int kk = 0; kk < 4; ++kk)
            am[mt][kk] = *(const bf16x8*)(az + lds_off(r0 + mt * 16 + lrow,
                                                       kk * 64 + grp * 16));
#pragma unroll
    for (int kk = 0; kk < 4; ++kk)
#pragma unroll
        for (int n = 0; n < 8; ++n) {
            bf16x8 b = *(const bf16x8*)(wb + lds_off(n * 16 + lrow,
                                                     kk * 64 + grp * 16));
#pragma unroll
            for (int mt = 0; mt < 2; ++mt)
                acc[mt][n] = __builtin_amdgcn_mfma_f32_16x16x32_bf16(
                    am[mt][kk], b, acc[mt][n], 0, 0, 0);
        }
}

// ---------------------------------------------------------------- layer 1 (MFMA, all-bf16)
__global__ __launch_bounds__(256, 2)
void layer1_kernel(const __bf16* __restrict__ xr, const __bf16* __restrict__ f1,
                   const __bf16* __restrict__ f2, const __bf16* __restrict__ f3,
                   const __bf16* __restrict__ wt1, const float* __restrict__ b1,
                   const __bf16* __restrict__ wt2, const float* __restrict__ b2,
                   __bf16* __restrict__ x1out)
{
    __shared__ uint4 lds_u4[4096];
    char* AZ = (char*)lds_u4;
    char* WB = (char*)lds_u4 + 32768;
    const int tid = threadIdx.x;
    const int lane = tid & 63;
    const int w = tid >> 6;
    const int r0 = w * 32;
    const int lrow = lane & 15;
    const int grp = lane >> 4;
    const int row0 = blockIdx.x * 128;

    f32x4 Y[2][8];
#pragma unroll
    for (int mt = 0; mt < 2; ++mt)
#pragma unroll
        for (int n = 0; n < 8; ++n) Y[mt][n] = {0.f, 0.f, 0.f, 0.f};

    for (int h = 0; h < 4; ++h) {
        const __bf16* feat = (h == 0) ? xr : (h == 1) ? f1 : (h == 2) ? f2 : f3;
        __syncthreads();
        stage_async(AZ, (const char*)(feat + (size_t)row0 * 128), w, lane);
        stage_async(WB, (const char*)(wt1 + (size_t)h * 16384), w, lane);
        __syncthreads();

        mfma_relu_phase(AZ, WB, b1 + h * 128, r0, lrow, grp);

        __syncthreads();
        stage_async(WB, (const char*)(wt2 + (size_t)h * 16384), w, lane);
        __syncthreads();
        mfma_phase(AZ, WB, r0, lrow, grp, Y);
    }

#pragma unroll
    for (int n = 0; n < 8; ++n) {
        int cc = n * 16 + lrow;
        float bs = b2[cc] + b2[128 + cc] + b2[256 + cc] + b2[384 + cc];
#pragma unroll
        for (int mt = 0; mt < 2; ++mt)
#pragma unroll
            for (int rg = 0; rg < 4; ++rg) {
                int zr = r0 + mt * 16 + grp * 4 + rg;
                *(__bf16*)(AZ + lds_off(zr, cc * 2)) = (__bf16)(Y[mt][n][rg] + bs);
            }
    }
    __syncthreads();
#pragma unroll
    for (int it = 0; it < 8; ++it) {
        int f = tid + it * 256;
        int r = f >> 4, o = f & 15;
        uint4 v = *(const uint4*)(AZ + lds_off(r, o * 16));
        *(uint4*)(x1out + (size_t)(row0 + r) * 128 + o * 8) = v;
    }
}

// ---------------------------------------------------------------- layer 2 + lin + pool (MFMA)
__global__ __launch_bounds__(256, 2)
void layer2_kernel(const __bf16* __restrict__ x1b, const __bf16* __restrict__ s1,
                   const __bf16* __restrict__ s2, const __bf16* __restrict__ s3,
                   const __bf16* __restrict__ wt1, const float* __restrict__ b1,
                   const __bf16* __restrict__ wt2, const float* __restrict__ b2,
                   const __bf16* __restrict__ wtl, const float* __restrict__ linb,
                   const int* __restrict__ batch, float* __restrict__ dout)
{
    __shared__ uint4 lds_u4[4096];
    char* AZ = (char*)lds_u4;
    char* WB = (char*)lds_u4 + 32768;
    const int tid = threadIdx.x;
    const int lane = tid & 63;
    const int w = tid >> 6;
    const int r0 = w * 32;
    const int lrow = lane & 15;
    const int grp = lane >> 4;
    const int row0 = blockIdx.x * 128;

    f32x4 Y[2][8];
#pragma unroll
    for (int mt = 0; mt < 2; ++mt)
#pragma unroll
        for (int n = 0; n < 8; ++n) Y[mt][n] = {0.f, 0.f, 0.f, 0.f};

    for (int h = 0; h < 4; ++h) {
        const __bf16* feat = (h == 0) ? x1b : (h == 1) ? s1 : (h == 2) ? s2 : s3;
        __syncthreads();
        stage_async(AZ, (const char*)(feat + (size_t)row0 * 128), w, lane);
        stage_async(WB, (const char*)(wt1 + (size_t)h * 16384), w, lane);
        __syncthreads();

        mfma_relu_phase(AZ, WB, b1 + h * 128, r0, lrow, grp);

        __syncthreads();
        stage_async(WB, (const char*)(wt2 + (size_t)h * 16384), w, lane);
        __syncthreads();
        mfma_phase(AZ, WB, r0, lrow, grp, Y);
    }

#pragma unroll
    for (int n = 0; n < 8; ++n) {
        int cc = n * 16 + lrow;
        float bs = b2[cc] + b2[128 + cc] + b2[256 + cc] + b2[384 + cc];
#pragma unroll
        for (int mt = 0; mt < 2; ++mt)
#pragma unroll
            for (int rg = 0; rg < 4; ++rg) {
                float v = Y[mt][n][rg] + bs;
                int zr = r0 + mt * 16 + grp * 4 + rg;
                *(__bf16*)(AZ + lds_off(zr, (n * 16 + lrow) * 2)) = (__bf16)v;
            }
    }
    __syncthreads();
    stage_async(WB, (const char*)(wtl + 16384), w, lane);
    __syncthreads();

    f32x4 o[2][8];
#pragma unroll
    for (int mt = 0; mt < 2; ++mt)
#pragma unroll
        for (int n = 0; n < 8; ++n) o[mt][n] = {0.f, 0.f, 0.f, 0.f};
    mfma_phase(AZ, WB, r0, lrow, grp, o);

    __syncthreads();
    stage_async(AZ, (const char*)(x1b + (size_t)row0 * 128), w, lane);
    stage_async(WB, (const char*)wtl, w, lane);
    __syncthreads();
    mfma_phase(AZ, WB, r0, lrow, grp, o);

    __syncthreads();
    float* tile32 = (float*)lds_u4;
#pragma unroll
    for (int n = 0; n < 8; ++n) {
        int cc = n * 16 + lrow;
        float lb = linb[cc];
#pragma unroll
        for (int mt = 0; mt < 2; ++mt)
#pragma unroll
            for (int rg = 0; rg < 4; ++rg) {
                int rl = r0 + mt * 16 + grp * 4 + rg;
                tile32[rl * 128 + cc] = o[mt][n][rg] + lb;
            }
    }
    __syncthreads();

    if (tid < 128) {
        const int d = tid;
        float acc = 0.f;
        int cur = batch[row0];
        for (int r = 0; r < 128; ++r) {
            int b = batch[row0 + r];
            if (b != cur) {
                atomicAdd(dout + (size_t)cur * 128 + d, acc);
                acc = 0.f;
                cur = b;
            }
            acc += tile32[r * 128 + d];
        }
        atomicAdd(dout + (size_t)cur * 128 + d, acc);
    }
}

// ---------------------------------------------------------------- launch
extern "C" void kernel_launch(void* const* d_in, const int* in_sizes, int n_in,
                              void* d_out, int out_size, void* d_ws, size_t ws_size,
                              hipStream_t stream) {
    (void)in_sizes; (void)n_in; (void)out_size; (void)ws_size;

    const float* x    = (const float*)d_in[0];
    const float* rw   = (const float*)d_in[1];
    const float* f1   = (const float*)d_in[2];
    const float* f2   = (const float*)d_in[3];
    const float* f3   = (const float*)d_in[4];
    const int*   e1   = (const int*)d_in[5];
    const int*   e2   = (const int*)d_in[6];
    const int*   e3   = (const int*)d_in[7];
    const int*   batch= (const int*)d_in[8];
    const float* l1w1 = (const float*)d_in[9];
    const float* l1b1 = (const float*)d_in[10];
    const float* l1w2 = (const float*)d_in[11];
    const float* l1b2 = (const float*)d_in[12];
    const float* l2w1 = (const float*)d_in[13];
    const float* l2b1 = (const float*)d_in[14];
    const float* l2w2 = (const float*)d_in[15];
    const float* l2b2 = (const float*)d_in[16];
    const float* linw = (const float*)d_in[17];
    const float* linb = (const float*)d_in[18];

    float* out = (float*)d_out;

    // workspace layout
    __bf16* x1b = (__bf16*)d_ws;
    __bf16* s1b = x1b + (size_t)N_NODES * 128;
    __bf16* s2b = s1b + (size_t)N_NODES * 128;
    __bf16* s3b = s2b + (size_t)N_NODES * 128;
    __bf16* wt  = s3b + (size_t)N_NODES * 128;
    __bf16* wt_l1w1 = wt;
    __bf16* wt_l1w2 = wt + 4 * 16384;
    __bf16* wt_l2w1 = wt + 8 * 16384;
    __bf16* wt_l2w2 = wt + 12 * 16384;
    __bf16* wt_lin  = wt + 16 * 16384;
    int* ibase  = (int*)(wt + 18 * 16384);
    int* offs3  = ibase;                                    // 3*(N+1)
    int* gcount = offs3 + (size_t)3 * (N_NODES + 1);        // 3*NSL*NW
    int* baseo  = gcount + (size_t)3 * NSL * NW;            // 3*NW*NSL
    int* wbase  = baseo + (size_t)3 * NW * NSL;             // 3*(NW+1)
    int* buf    = wbase + (size_t)3 * (NW + 1);             // 3*NEDGE (packed)
    int* cols   = buf + (size_t)3 * NEDGE;                  // 3*NEDGE
    uint2* cnts3 = (uint2*)(cols + (size_t)3 * NEDGE);      // 3*N (packed counts)
    __bf16* xrb = (__bf16*)buf;   // bf16 concat(x,rw); consumed by layer1 BEFORE
                                  // bucket_kernel overwrites buf (stream-ordered)

    // prep: weights + features -> bf16
    tr_kernel<<<256, 256, 0, stream>>>(l1w1, wt_l1w1, 4);
    tr_kernel<<<256, 256, 0, stream>>>(l1w2, wt_l1w2, 4);
    tr_kernel<<<256, 256, 0, stream>>>(l2w1, wt_l2w1, 4);
    tr_kernel<<<256, 256, 0, stream>>>(l2w2, wt_l2w2, 4);
    tr_kernel<<<128, 256, 0, stream>>>(linw, wt_lin, 2);

    cvt_cat_kernel<<<4096, 256, 0, stream>>>(x, rw, xrb);
    cvt_kernel<<<4096, 256, 0, stream>>>(f1, s1b);
    cvt_kernel<<<4096, 256, 0, stream>>>(f2, s2b);
    cvt_kernel<<<4096, 256, 0, stream>>>(f3, s3b);

    zero_kernel<<<64, 256, 0, stream>>>((floatx4*)out, (long)NGRAPH * 32);

    layer1_kernel<<<N_NODES / 128, 256, 0, stream>>>(
        xrb, s1b, s2b, s3b, wt_l1w1, l1b1, wt_l1w2, l1b2, x1b);

    // CSR build v4: LDS-sorted bucket, (row, colwindow)-sorted col assembly
    wincount_kernel<<<3 * NSL, 256, 0, stream>>>(e1, e2, e3, gcount);
    basescan_kernel<<<3, 256, 0, stream>>>(gcount, baseo, wbase);
    bucket_kernel<<<3 * NSL, 256, 0, stream>>>(e1, e2, e3, baseo, buf);
    winbuild_kernel<<<3 * NW, 256, 0, stream>>>(buf, wbase, offs3, cols, cnts3);

    __bf16* ss[3] = {s1b, s2b, s3b};
    for (int hop = 0; hop < 3; ++hop) {
        csr_spmm_kernel<<<N_NODES / (4 * SP_BATCH), 256, 0, stream>>>(
            offs3 + (size_t)hop * (N_NODES + 1),
            (const unsigned char*)(cnts3 + (size_t)hop * N_NODES),
            cols + (size_t)hop * NEDGE, x1b, ss[hop]);
    }

    layer2_kernel<<<N_NODES / 128, 256, 0, stream>>>(
        x1b, s1b, s2b, s3b, wt_l2w1, l2b1, wt_l2w2, l2b2, wt_lin, linb, batch, out);
}

// Round 18
// 896.171 us; speedup vs baseline: 1.8314x; 1.8314x over previous
//
#include <hip/hip_runtime.h>

#define N_NODES 131072
#define DIM     128
#define NGRAPH  1024
#define NEDGE   4194304

#define NW      512                   // windows
#define WBINS   256                   // rows (bins) per window
#define NSL     512                   // edge slices per hop
#define SLICE_E (NEDGE / NSL)         // 8192 edges per slice
#define CAP     12288                 // LDS col-image capacity (ints); mean 8192

typedef float floatx4 __attribute__((ext_vector_type(4)));
typedef float f32x4  __attribute__((ext_vector_type(4)));
typedef __bf16 bf16x8 __attribute__((ext_vector_type(8)));
typedef __bf16 bf16x4 __attribute__((ext_vector_type(4)));

// swizzled LDS byte offset for a [rows][128] bf16 tile (row stride 256 B)
__device__ __forceinline__ int lds_off(int row, int kb) {
    return row * 256 + (kb ^ ((row & 7) << 4));
}

// async global->LDS, 16 B per lane; LDS dest = wave-uniform base + lane*16
#define GLOAD16(gp, lp) __builtin_amdgcn_global_load_lds( \
    (const __attribute__((address_space(1))) void*)(gp),  \
    (__attribute__((address_space(3))) void*)(lp), 16, 0, 0)

__device__ __forceinline__ void stage_async(char* dstbase, const char* src,
                                            int w, int lane) {
#pragma unroll
    for (int it = 0; it < 8; ++it) {
        int chunk = it * 4 + w;
        int p = chunk * 1024 + lane * 16;
        int r = p >> 8;
        int o = p & 255;
        const char* g = src + r * 256 + (o ^ ((r & 7) << 4));
        GLOAD16(g, dstbase + chunk * 1024);
    }
}

// ---------------------------------------------------------------- zero
__global__ __launch_bounds__(256)
void zero_kernel(floatx4* __restrict__ p, long n4) {
    long i = (long)blockIdx.x * blockDim.x + threadIdx.x;
    long stride = (long)gridDim.x * blockDim.x;
    floatx4 z = {0.f, 0.f, 0.f, 0.f};
    for (; i < n4; i += stride) p[i] = z;
}

// ---------------------------------------------------------------- prep: fp32 -> bf16
__global__ __launch_bounds__(256)
void cvt_kernel(const float* __restrict__ src, __bf16* __restrict__ dst) {
    int i = blockIdx.x * 256 + threadIdx.x;
    const int stride = gridDim.x * 256;
    const int total = N_NODES * 32;
    for (; i < total; i += stride) {
        floatx4 v = ((const floatx4*)src)[i];
        bf16x4 h;
        h[0] = (__bf16)v[0]; h[1] = (__bf16)v[1];
        h[2] = (__bf16)v[2]; h[3] = (__bf16)v[3];
        ((bf16x4*)dst)[i] = h;
    }
}

__global__ __launch_bounds__(256)
void cvt_cat_kernel(const float* __restrict__ x, const float* __restrict__ rw,
                    __bf16* __restrict__ dst) {
    int i = blockIdx.x * 256 + threadIdx.x;
    const int stride = gridDim.x * 256;
    const int total = N_NODES * 32;
    for (; i < total; i += stride) {
        int rowg = i >> 5, g = i & 31;
        const float* s = (g < 16) ? x  + (size_t)rowg * 64 + g * 4
                                  : rw + (size_t)rowg * 64 + (g - 16) * 4;
        floatx4 v = *(const floatx4*)s;
        bf16x4 h;
        h[0] = (__bf16)v[0]; h[1] = (__bf16)v[1];
        h[2] = (__bf16)v[2]; h[3] = (__bf16)v[3];
        *(bf16x4*)(dst + (size_t)rowg * 128 + g * 4) = h;
    }
}

// ---------------------------------------------------------------- weight prep
__global__ __launch_bounds__(256)
void tr_kernel(const float* __restrict__ src, __bf16* __restrict__ dst, int nmat) {
    int idx = blockIdx.x * blockDim.x + threadIdx.x;
    int total = nmat * 16384;
    if (idx >= total) return;
    int m = idx >> 14;
    int col = (idx >> 7) & 127;
    int k = idx & 127;
    dst[idx] = (__bf16)src[m * 16384 + k * 128 + col];
}

// ---------------------------------------------------------------- CSR build v3
__global__ __launch_bounds__(256)
void wincount_kernel(const int* __restrict__ e1, const int* __restrict__ e2,
                     const int* __restrict__ e3, int* __restrict__ gcount) {
    const int gb = blockIdx.x;
    const int sl = gb % NSL;
    const int hop = gb / NSL;
    const int* rows = hop == 0 ? e1 : hop == 1 ? e2 : e3;

    __shared__ int cnt[NW];
    for (int i = threadIdx.x; i < NW; i += 256) cnt[i] = 0;
    __syncthreads();

    const int4* src = (const int4*)rows + (size_t)sl * (SLICE_E / 4);
    for (int j = threadIdx.x; j < SLICE_E / 4; j += 256) {
        int4 v = src[j];
        atomicAdd(&cnt[v.x >> 8], 1); atomicAdd(&cnt[v.y >> 8], 1);
        atomicAdd(&cnt[v.z >> 8], 1); atomicAdd(&cnt[v.w >> 8], 1);
    }
    __syncthreads();

    int* dst = gcount + ((size_t)hop * NSL + sl) * NW;
    for (int i = threadIdx.x; i < NW; i += 256) dst[i] = cnt[i];
}

__global__ __launch_bounds__(256)
void basescan_kernel(const int* __restrict__ gcount, int* __restrict__ baseo,
                     int* __restrict__ wbase) {
    const int hop = blockIdx.x;
    const int t = threadIdx.x;
    __shared__ int wt[NW];
    __shared__ int part[256];

    for (int k = 0; k < 2; ++k) {
        int w = t * 2 + k;
        int s = 0;
        for (int sl = 0; sl < NSL; ++sl)
            s += gcount[((size_t)hop * NSL + sl) * NW + w];
        wt[w] = s;
    }
    __syncthreads();
    part[t] = wt[2 * t] + wt[2 * t + 1];
    __syncthreads();
    for (int d = 1; d < 256; d <<= 1) {
        int v = (t >= d) ? part[t - d] : 0;
        __syncthreads();
        part[t] += v;
        __syncthreads();
    }
    int run = (t == 0) ? 0 : part[t - 1];
    for (int k = 0; k < 2; ++k) {
        int w = 2 * t + k;
        wbase[hop * (NW + 1) + w] = run;
        int r2 = run;
        for (int sl = 0; sl < NSL; ++sl) {
            baseo[((size_t)hop * NW + w) * NSL + sl] = r2;
            r2 += gcount[((size_t)hop * NSL + sl) * NW + w];
        }
        run += wt[w];
    }
    if (t == 255) wbase[hop * (NW + 1) + NW] = NEDGE;
}

// bucket v3: per (hop,slice) in-LDS counting sort by window, then
// segment-contiguous write-out (each 64B line fully written in one burst).
__global__ __launch_bounds__(256)
void bucket_kernel(const int* __restrict__ e1, const int* __restrict__ e2,
                   const int* __restrict__ e3, const int* __restrict__ baseo,
                   int* __restrict__ buf) {
    const int gb = blockIdx.x;
    const int sl = gb % NSL;
    const int hop = gb / NSL;
    const int* rows = hop == 0 ? e1 : hop == 1 ? e2 : e3;
    const int* cs = rows + NEDGE;
    const int t = threadIdx.x;

    __shared__ int hist[NW];          // histogram, then cursors
    __shared__ int segstart[NW + 1];
    __shared__ int part[256];
    __shared__ int image[SLICE_E];    // 32 KB

    for (int i = t; i < NW; i += 256) hist[i] = 0;
    __syncthreads();

    const int4* r4 = (const int4*)rows + (size_t)sl * (SLICE_E / 4);
    const int4* c4 = (const int4*)cs + (size_t)sl * (SLICE_E / 4);
    for (int j = t; j < SLICE_E / 4; j += 256) {
        int4 v = r4[j];
        atomicAdd(&hist[v.x >> 8], 1); atomicAdd(&hist[v.y >> 8], 1);
        atomicAdd(&hist[v.z >> 8], 1); atomicAdd(&hist[v.w >> 8], 1);
    }
    __syncthreads();

    int a = hist[2 * t], b = hist[2 * t + 1];
    part[t] = a + b;
    __syncthreads();
    for (int d = 1; d < 256; d <<= 1) {
        int v = (t >= d) ? part[t - d] : 0;
        __syncthreads();
        part[t] += v;
        __syncthreads();
    }
    int base = (t == 0) ? 0 : part[t - 1];
    segstart[2 * t] = base;
    segstart[2 * t + 1] = base + a;
    if (t == 255) segstart[NW] = SLICE_E;
    __syncthreads();
    hist[2 * t] = base;
    hist[2 * t + 1] = base + a;
    __syncthreads();

    for (int j = t; j < SLICE_E / 4; j += 256) {
        int4 r = r4[j];
        int4 c = c4[j];
        int p;
        p = atomicAdd(&hist[r.x >> 8], 1); image[p] = ((r.x & 255) << 17) | c.x;
        p = atomicAdd(&hist[r.y >> 8], 1); image[p] = ((r.y & 255) << 17) | c.y;
        p = atomicAdd(&hist[r.z >> 8], 1); image[p] = ((r.z & 255) << 17) | c.z;
        p = atomicAdd(&hist[r.w >> 8], 1); image[p] = ((r.w & 255) << 17) | c.w;
    }
    __syncthreads();

    int* bufh = buf + (size_t)hop * NEDGE;
    const int* bo = baseo + (size_t)hop * NW * NSL + sl;
    for (int j = t; j < SLICE_E; j += 256) {
        int lo = 0, hi = NW;
        while (hi - lo > 1) {
            int mid = (lo + hi) >> 1;
            if (segstart[mid] <= j) lo = mid; else hi = mid;
        }
        int dst = bo[(size_t)lo * NSL] + (j - segstart[lo]);
        bufh[dst] = image[j];
    }
}

__global__ __launch_bounds__(256)
void winbuild_kernel(const int* __restrict__ buf, const int* __restrict__ wbase,
                     int* __restrict__ offs3, int* __restrict__ cols) {
    const int gb = blockIdx.x;
    const int w = gb % NW;
    const int hop = gb / NW;
    const int b0 = wbase[hop * (NW + 1) + w];
    const int b1 = wbase[hop * (NW + 1) + w + 1];
    const int tot = b1 - b0;
    const int* src = buf + (size_t)hop * NEDGE + b0;
    int* col = cols + (size_t)hop * NEDGE;
    int* offs = offs3 + (size_t)hop * (N_NODES + 1);
    const int t = threadIdx.x;

    __shared__ int hist[WBINS];
    __shared__ int scanb[WBINS];
    __shared__ int image[CAP];

    hist[t] = 0;
    __syncthreads();
    for (int i = t; i < tot; i += 256) atomicAdd(&hist[src[i] >> 17], 1);
    __syncthreads();

    int v = hist[t];
    scanb[t] = v;
    __syncthreads();
    for (int d = 1; d < 256; d <<= 1) {
        int u = (t >= d) ? scanb[t - d] : 0;
        __syncthreads();
        scanb[t] += u;
        __syncthreads();
    }
    const int excl = scanb[t] - v;

    offs[w * WBINS + t] = b0 + excl;
    if (w == NW - 1 && t == 0) offs[N_NODES] = NEDGE;
    __syncthreads();

    if (tot <= CAP) {
        hist[t] = excl;
        __syncthreads();
        for (int i = t; i < tot; i += 256) {
            int e = src[i];
            int p = atomicAdd(&hist[e >> 17], 1);
            image[p] = e & 0x1FFFF;
        }
        __syncthreads();
        for (int i = t; i < tot; i += 256) col[b0 + i] = image[i];
    } else {
        hist[t] = b0 + excl;
        __syncthreads();
        for (int i = t; i < tot; i += 256) {
            int e = src[i];
            int p = atomicAdd(&hist[e >> 17], 1);
            col[p] = e & 0x1FFFF;
        }
    }
}

// ---------------------------------------------------------------- CSR spmm (bf16)
// merged over 3 hops: one row per wave; s1/s2/s3 and cols/offs contiguous.
__global__ __launch_bounds__(256)
void csr_spmm_kernel(const int* __restrict__ offs3, const int* __restrict__ cols,
                     const __bf16* __restrict__ xin, __bf16* __restrict__ sbase) {
    const int lane = threadIdx.x & 63;
    const int gr = blockIdx.x * (blockDim.x >> 6) + (threadIdx.x >> 6);
    const int hop = gr >> 17;                 // N_NODES = 1<<17
    const int row = gr & (N_NODES - 1);
    const int* offs = offs3 + (size_t)hop * (N_NODES + 1);
    const int* col = cols + (size_t)hop * NEDGE;
    __bf16* outb = sbase + (size_t)hop * N_NODES * 128;

    const int beg = offs[row];
    const int end = offs[row + 1];

    float a0 = 0.f, a1 = 0.f, b0 = 0.f, b1 = 0.f;
    float c0f = 0.f, c1f = 0.f, d0 = 0.f, d1 = 0.f;
    for (int b = beg; b < end; b += 64) {
        const int n = min(64, end - b);
        int cidx = (b + lane < end) ? col[b + lane] : 0;
        int i = 0;
        for (; i + 4 <= n; i += 4) {
            int e0 = __shfl(cidx, i);
            int e1 = __shfl(cidx, i + 1);
            int e2 = __shfl(cidx, i + 2);
            int e3 = __shfl(cidx, i + 3);
            unsigned v0 = *(const unsigned*)(xin + (size_t)e0 * 128 + lane * 2);
            unsigned v1 = *(const unsigned*)(xin + (size_t)e1 * 128 + lane * 2);
            unsigned v2 = *(const unsigned*)(xin + (size_t)e2 * 128 + lane * 2);
            unsigned v3 = *(const unsigned*)(xin + (size_t)e3 * 128 + lane * 2);
            a0 += __uint_as_float(v0 << 16); a1 += __uint_as_float(v0 & 0xffff0000u);
            b0 += __uint_as_float(v1 << 16); b1 += __uint_as_float(v1 & 0xffff0000u);
            c0f += __uint_as_float(v2 << 16); c1f += __uint_as_float(v2 & 0xffff0000u);
            d0 += __uint_as_float(v3 << 16); d1 += __uint_as_float(v3 & 0xffff0000u);
        }
        for (; i < n; ++i) {
            int e = __shfl(cidx, i);
            unsigned v = *(const unsigned*)(xin + (size_t)e * 128 + lane * 2);
            a0 += __uint_as_float(v << 16); a1 += __uint_as_float(v & 0xffff0000u);
        }
    }
    float o0 = a0 + b0 + c0f + d0;
    float o1 = a1 + b1 + c1f + d1;
    union { unsigned u; __bf16 h[2]; } pk;
    pk.h[0] = (__bf16)o0; pk.h[1] = (__bf16)o1;
    *(unsigned*)(outb + (size_t)row * 128 + lane * 2) = pk.u;
}

// ---------------------------------------------------------------- GEMM phases
__device__ __forceinline__ void mfma_relu_phase(char* az, const char* wb,
                                                const float* bias,
                                                int r0, int lrow, int grp) {
    bf16x8 am[2][4];
#pragma unroll
    for (int mt = 0; mt < 2; ++mt)
#pragma unroll
        for (int kk = 0; kk < 4; ++kk)
            am[mt][kk] = *(const bf16x8*)(az + lds_off(r0 + mt * 16 + lrow,
                                                       kk * 64 + grp * 16));
#pragma unroll
    for (int n = 0; n < 8; ++n) {
        f32x4 a0 = {0.f, 0.f, 0.f, 0.f};
        f32x4 a1 = {0.f, 0.f, 0.f, 0.f};
#pragma unroll
        for (int kk = 0; kk < 4; ++kk) {
            bf16x8 b = *(const bf16x8*)(wb + lds_off(n * 16 + lrow,
                                                     kk * 64 + grp * 16));
            a0 = __builtin_amdgcn_mfma_f32_16x16x32_bf16(am[0][kk], b, a0, 0, 0, 0);
            a1 = __builtin_amdgcn_mfma_f32_16x16x32_bf16(am[1][kk], b, a1, 0, 0, 0);
        }
        float bs = bias[n * 16 + lrow];
#pragma unroll
        for (int rg = 0; rg < 4; ++rg) {
            float v0 = fmaxf(a0[rg] + bs, 0.f);
            float v1 = fmaxf(a1[rg] + bs, 0.f);
            *(__bf16*)(az + lds_off(r0 + grp * 4 + rg, (n * 16 + lrow) * 2)) = (__bf16)v0;
            *(__bf16*)(az + lds_off(r0 + 16 + grp * 4 + rg, (n * 16 + lrow) * 2)) = (__bf16)v1;
        }
    }
}

__device__ __forceinline__ void mfma_phase(const char* az, const char* wb,
                                           int r0, int lrow, int grp,
                                           f32x4 (&acc)[2][8]) {
    bf16x8 am[2][4];
#pragma unroll
    for (int mt = 0; mt < 2; ++mt)
#pragma unroll
        for (int kk = 0; kk < 4; ++kk)
            am[mt][kk] = *(const bf16x8*)(az + lds_off(r0 + mt * 16 + lrow,
                                                       kk * 64 + grp * 16));
#pragma unroll
    for (int kk = 0; kk < 4; ++kk)
#pragma unroll
        for (int n = 0; n < 8; ++n) {
            bf16x8 b = *(const bf16x8*)(wb + lds_off(n * 16 + lrow,
                                                     kk * 64 + grp * 16));
#pragma unroll
            for (int mt = 0; mt < 2; ++mt)
                acc[mt][n] = __builtin_amdgcn_mfma_f32_16x16x32_bf16(
                    am[mt][kk], b, acc[mt][n], 0, 0, 0);
        }
}

// ---------------------------------------------------------------- layer 1 (MFMA, all-bf16)
__global__ __launch_bounds__(256, 2)
void layer1_kernel(const __bf16* __restrict__ xr, const __bf16* __restrict__ f1,
                   const __bf16* __restrict__ f2, const __bf16* __restrict__ f3,
                   const __bf16* __restrict__ wt1, const float* __restrict__ b1,
                   const __bf16* __restrict__ wt2, const float* __restrict__ b2,
                   __bf16* __restrict__ x1out)
{
    __shared__ uint4 lds_u4[4096];
    char* AZ = (char*)lds_u4;
    char* WB = (char*)lds_u4 + 32768;
    const int tid = threadIdx.x;
    const int lane = tid & 63;
    const int w = tid >> 6;
    const int r0 = w * 32;
    const int lrow = lane & 15;
    const int grp = lane >> 4;
    const int row0 = blockIdx.x * 128;

    f32x4 Y[2][8];
#pragma unroll
    for (int mt = 0; mt < 2; ++mt)
#pragma unroll
        for (int n = 0; n < 8; ++n) Y[mt][n] = {0.f, 0.f, 0.f, 0.f};

    for (int h = 0; h < 4; ++h) {
        const __bf16* feat = (h == 0) ? xr : (h == 1) ? f1 : (h == 2) ? f2 : f3;
        __syncthreads();
        stage_async(AZ, (const char*)(feat + (size_t)row0 * 128), w, lane);
        stage_async(WB, (const char*)(wt1 + (size_t)h * 16384), w, lane);
        __syncthreads();

        mfma_relu_phase(AZ, WB, b1 + h * 128, r0, lrow, grp);

        __syncthreads();
        stage_async(WB, (const char*)(wt2 + (size_t)h * 16384), w, lane);
        __syncthreads();
        mfma_phase(AZ, WB, r0, lrow, grp, Y);
    }

#pragma unroll
    for (int n = 0; n < 8; ++n) {
        int cc = n * 16 + lrow;
        float bs = b2[cc] + b2[128 + cc] + b2[256 + cc] + b2[384 + cc];
#pragma unroll
        for (int mt = 0; mt < 2; ++mt)
#pragma unroll
            for (int rg = 0; rg < 4; ++rg) {
                int zr = r0 + mt * 16 + grp * 4 + rg;
                *(__bf16*)(AZ + lds_off(zr, cc * 2)) = (__bf16)(Y[mt][n][rg] + bs);
            }
    }
    __syncthreads();
#pragma unroll
    for (int it = 0; it < 8; ++it) {
        int f = tid + it * 256;
        int r = f >> 4, o = f & 15;
        uint4 v = *(const uint4*)(AZ + lds_off(r, o * 16));
        *(uint4*)(x1out + (size_t)(row0 + r) * 128 + o * 8) = v;
    }
}

// ---------------------------------------------------------------- layer 2 + lin + pool (MFMA)
__global__ __launch_bounds__(256, 2)
void layer2_kernel(const __bf16* __restrict__ x1b, const __bf16* __restrict__ s1,
                   const __bf16* __restrict__ s2, const __bf16* __restrict__ s3,
                   const __bf16* __restrict__ wt1, const float* __restrict__ b1,
                   const __bf16* __restrict__ wt2, const float* __restrict__ b2,
                   const __bf16* __restrict__ wtl, const float* __restrict__ linb,
                   const int* __restrict__ batch, float* __restrict__ dout)
{
    __shared__ uint4 lds_u4[4096];
    char* AZ = (char*)lds_u4;
    char* WB = (char*)lds_u4 + 32768;
    const int tid = threadIdx.x;
    const int lane = tid & 63;
    const int w = tid >> 6;
    const int r0 = w * 32;
    const int lrow = lane & 15;
    const int grp = lane >> 4;
    const int row0 = blockIdx.x * 128;

    f32x4 Y[2][8];
#pragma unroll
    for (int mt = 0; mt < 2; ++mt)
#pragma unroll
        for (int n = 0; n < 8; ++n) Y[mt][n] = {0.f, 0.f, 0.f, 0.f};

    for (int h = 0; h < 4; ++h) {
        const __bf16* feat = (h == 0) ? x1b : (h == 1) ? s1 : (h == 2) ? s2 : s3;
        __syncthreads();
        stage_async(AZ, (const char*)(feat + (size_t)row0 * 128), w, lane);
        stage_async(WB, (const char*)(wt1 + (size_t)h * 16384), w, lane);
        __syncthreads();

        mfma_relu_phase(AZ, WB, b1 + h * 128, r0, lrow, grp);

        __syncthreads();
        stage_async(WB, (const char*)(wt2 + (size_t)h * 16384), w, lane);
        __syncthreads();
        mfma_phase(AZ, WB, r0, lrow, grp, Y);
    }

#pragma unroll
    for (int n = 0; n < 8; ++n) {
        int cc = n * 16 + lrow;
        float bs = b2[cc] + b2[128 + cc] + b2[256 + cc] + b2[384 + cc];
#pragma unroll
        for (int mt = 0; mt < 2; ++mt)
#pragma unroll
            for (int rg = 0; rg < 4; ++rg) {
                float v = Y[mt][n][rg] + bs;
                int zr = r0 + mt * 16 + grp * 4 + rg;
                *(__bf16*)(AZ + lds_off(zr, (n * 16 + lrow) * 2)) = (__bf16)v;
            }
    }
    __syncthreads();
    stage_async(WB, (const char*)(wtl + 16384), w, lane);
    __syncthreads();

    f32x4 o[2][8];
#pragma unroll
    for (int mt = 0; mt < 2; ++mt)
#pragma unroll
        for (int n = 0; n < 8; ++n) o[mt][n] = {0.f, 0.f, 0.f, 0.f};
    mfma_phase(AZ, WB, r0, lrow, grp, o);

    __syncthreads();
    stage_async(AZ, (const char*)(x1b + (size_t)row0 * 128), w, lane);
    stage_async(WB, (const char*)wtl, w, lane);
    __syncthreads();
    mfma_phase(AZ, WB, r0, lrow, grp, o);

    __syncthreads();
    float* tile32 = (float*)lds_u4;
#pragma unroll
    for (int n = 0; n < 8; ++n) {
        int cc = n * 16 + lrow;
        float lb = linb[cc];
#pragma unroll
        for (int mt = 0; mt < 2; ++mt)
#pragma unroll
            for (int rg = 0; rg < 4; ++rg) {
                int rl = r0 + mt * 16 + grp * 4 + rg;
                tile32[rl * 128 + cc] = o[mt][n][rg] + lb;
            }
    }
    __syncthreads();

    if (tid < 128) {
        const int d = tid;
        float acc = 0.f;
        int cur = batch[row0];
        for (int r = 0; r < 128; ++r) {
            int b = batch[row0 + r];
            if (b != cur) {
                atomicAdd(dout + (size_t)cur * 128 + d, acc);
                acc = 0.f;
                cur = b;
            }
            acc += tile32[r * 128 + d];
        }
        atomicAdd(dout + (size_t)cur * 128 + d, acc);
    }
}

// ---------------------------------------------------------------- launch
extern "C" void kernel_launch(void* const* d_in, const int* in_sizes, int n_in,
                              void* d_out, int out_size, void* d_ws, size_t ws_size,
                              hipStream_t stream) {
    (void)in_sizes; (void)n_in; (void)out_size; (void)ws_size;

    const float* x    = (const float*)d_in[0];
    const float* rw   = (const float*)d_in[1];
    const float* f1   = (const float*)d_in[2];
    const float* f2   = (const float*)d_in[3];
    const float* f3   = (const float*)d_in[4];
    const int*   e1   = (const int*)d_in[5];
    const int*   e2   = (const int*)d_in[6];
    const int*   e3   = (const int*)d_in[7];
    const int*   batch= (const int*)d_in[8];
    const float* l1w1 = (const float*)d_in[9];
    const float* l1b1 = (const float*)d_in[10];
    const float* l1w2 = (const float*)d_in[11];
    const float* l1b2 = (const float*)d_in[12];
    const float* l2w1 = (const float*)d_in[13];
    const float* l2b1 = (const float*)d_in[14];
    const float* l2w2 = (const float*)d_in[15];
    const float* l2b2 = (const float*)d_in[16];
    const float* linw = (const float*)d_in[17];
    const float* linb = (const float*)d_in[18];

    float* out = (float*)d_out;

    // workspace layout
    __bf16* x1b = (__bf16*)d_ws;
    __bf16* s1b = x1b + (size_t)N_NODES * 128;
    __bf16* s2b = s1b + (size_t)N_NODES * 128;
    __bf16* s3b = s2b + (size_t)N_NODES * 128;
    __bf16* wt  = s3b + (size_t)N_NODES * 128;
    __bf16* wt_l1w1 = wt;
    __bf16* wt_l1w2 = wt + 4 * 16384;
    __bf16* wt_l2w1 = wt + 8 * 16384;
    __bf16* wt_l2w2 = wt + 12 * 16384;
    __bf16* wt_lin  = wt + 16 * 16384;
    int* ibase  = (int*)(wt + 18 * 16384);
    int* offs3  = ibase;                                    // 3*(N+1)
    int* gcount = offs3 + (size_t)3 * (N_NODES + 1);        // 3*NSL*NW
    int* baseo  = gcount + (size_t)3 * NSL * NW;            // 3*NW*NSL
    int* wbase  = baseo + (size_t)3 * NW * NSL;             // 3*(NW+1)
    int* buf    = wbase + (size_t)3 * (NW + 1);             // 3*NEDGE (packed)
    int* cols   = buf + (size_t)3 * NEDGE;                  // 3*NEDGE
    __bf16* xrb = (__bf16*)buf;   // bf16 concat(x,rw); consumed by layer1 BEFORE
                                  // bucket_kernel overwrites buf (stream-ordered)

    // prep: weights + features -> bf16
    tr_kernel<<<256, 256, 0, stream>>>(l1w1, wt_l1w1, 4);
    tr_kernel<<<256, 256, 0, stream>>>(l1w2, wt_l1w2, 4);
    tr_kernel<<<256, 256, 0, stream>>>(l2w1, wt_l2w1, 4);
    tr_kernel<<<256, 256, 0, stream>>>(l2w2, wt_l2w2, 4);
    tr_kernel<<<128, 256, 0, stream>>>(linw, wt_lin, 2);

    cvt_cat_kernel<<<4096, 256, 0, stream>>>(x, rw, xrb);
    cvt_kernel<<<4096, 256, 0, stream>>>(f1, s1b);
    cvt_kernel<<<4096, 256, 0, stream>>>(f2, s2b);
    cvt_kernel<<<4096, 256, 0, stream>>>(f3, s3b);

    zero_kernel<<<64, 256, 0, stream>>>((floatx4*)out, (long)NGRAPH * 32);

    layer1_kernel<<<N_NODES / 128, 256, 0, stream>>>(
        xrb, s1b, s2b, s3b, wt_l1w1, l1b1, wt_l1w2, l1b2, x1b);

    // CSR build v3: LDS-sorted bucket, coalesced col assembly
    wincount_kernel<<<3 * NSL, 256, 0, stream>>>(e1, e2, e3, gcount);
    basescan_kernel<<<3, 256, 0, stream>>>(gcount, baseo, wbase);
    bucket_kernel<<<3 * NSL, 256, 0, stream>>>(e1, e2, e3, baseo, buf);
    winbuild_kernel<<<3 * NW, 256, 0, stream>>>(buf, wbase, offs3, cols);

    // merged spmm: all 3 hops in one launch (shared x1 gather -> better L2 reuse)
    csr_spmm_kernel<<<3 * N_NODES / 4, 256, 0, stream>>>(offs3, cols, x1b, s1b);

    layer2_kernel<<<N_NODES / 128, 256, 0, stream>>>(
        x1b, s1b, s2b, s3b, wt_l2w1, l2b1, wt_l2w2, l2b2, wt_lin, linb, batch, out);
}